// Round 10
// baseline (216.402 us; speedup 1.0000x reference)
//
#include <hip/hip_runtime.h>
#include <math.h>

// ---- NSA hyperparameters (compile-time, matches reference config) ----
constexpr int kT    = 2048;
constexpr int kHQ   = 16;
constexpr int kD    = 128;
constexpr int kKS   = 32;
constexpr int kST   = 16;
constexpr int kBS   = 64;
constexpr int kM    = (kT - kKS) / kST + 1;   // 127 compressed tokens
constexpr int kNB   = (kT + kBS - 1) / kBS;   // 32 selection blocks
constexpr int kTopN = 16;
constexpr int kNInit = 2;
constexpr int kWIN  = 512;
constexpr float kNEG = -1e30f;
constexpr float kScale = 0.08838834764831845f;      // 128^-0.5
// log2-domain scores: fold log2(e) into the q scaling so every exp is a
// bare v_exp_f32 (exp2) with no preceding multiply.
constexpr float kScaleL2 = kScale * 1.4426950408889634f;

constexpr int kPS2 = 144;   // paired P slab row stride (fp16 halfwords; 128 used)
constexpr int kOC  = 36;    // lane stride for [64][32]-ish short arrays
constexpr int kUW  = 9472;  // per-wave union LDS region bytes

typedef __attribute__((ext_vector_type(8))) short short8;
typedef __attribute__((ext_vector_type(4))) short short4v;
typedef __attribute__((ext_vector_type(8))) _Float16 half8;
typedef __attribute__((ext_vector_type(4))) _Float16 half4v;
typedef __attribute__((ext_vector_type(4))) float floatx4;

// RNE float -> bf16 bits
__device__ inline short f2bf(float x) {
    unsigned u = __float_as_uint(x);
    unsigned r = (u + 0x7fffu + ((u >> 16) & 1u)) >> 16;
    return (short)r;
}
__device__ inline float b2f(short h) {
    return __uint_as_float(((unsigned)(unsigned short)h) << 16);
}

// ---------------------------------------------------------------------
// K1: FRAGMENT-ORDERED staging (R9-proven: all k_nsa loads are one
// coalesced lane-contiguous 1KB burst + immediate offsets).
//   kb2 [b][kt*4+c][lane][8]  = bf16 K[b*64+kt*16+(lane&15)][c*32+(lane>>4)*8+j]
//   vt2 [b][n8*2+kc][lane][8] = fp16 V[b*64+w][n8*16+(lane&15)],
//        col = kc*32+(lane>>4)*8+j, w = (col&3)*16 + (col>>2)  (key perm)
//   ck2h/ck2l [(mt*4+c)][lane][8] = bf16 hi/lo cmp_k frags
//   cv2 [(nt*4+c)][lane][8]  = bf16 cmpV^T with m-perm folded in
// blocks [0,32): kb2   [32,64): vt2 (LDS transpose)   [64,128): cmp
// ---------------------------------------------------------------------
__global__ __launch_bounds__(256) void k_stage(
        const float* __restrict__ k, const float* __restrict__ v,
        short* __restrict__ kb2, _Float16* __restrict__ vt2,
        short* __restrict__ ck2h, short* __restrict__ ck2l,
        short* __restrict__ cv2) {
    const int bid = blockIdx.x;
    const int tid = threadIdx.x;
    __shared__ _Float16 vls[64 * 132];

    if (bid < 32) {
        const int b = bid;
        #pragma unroll
        for (int p = 0; p < 4; ++p) {
            const int idx = p * 256 + tid;          // 0..1023 = g*64 + lane
            const int g = idx >> 6;                  // kt*4 + c
            const int lane2 = idx & 63;
            const int kt = g >> 2, c = g & 3;
            const int l15v = lane2 & 15, quadv = lane2 >> 4;
            const float* src = k + (size_t)(b * 64 + kt * 16 + l15v) * kD + c * 32 + quadv * 8;
            const float4 f0 = *(const float4*)(src);
            const float4 f1 = *(const float4*)(src + 4);
            short8 s;
            s[0] = f2bf(f0.x); s[1] = f2bf(f0.y); s[2] = f2bf(f0.z); s[3] = f2bf(f0.w);
            s[4] = f2bf(f1.x); s[5] = f2bf(f1.y); s[6] = f2bf(f1.z); s[7] = f2bf(f1.w);
            *(short8*)(kb2 + ((size_t)b * 1024 + idx) * 8) = s;
        }
    } else if (bid < 64) {
        const int b = bid - 32;
        #pragma unroll
        for (int p = 0; p < 8; ++p) {
            const int idx = p * 256 + tid;   // 2048 float4-slots
            const int r = idx >> 5;
            const int d4 = (idx & 31) * 4;
            const float4 f = *(const float4*)(v + (size_t)(b * 64 + r) * kD + d4);
            _Float16* dst = &vls[r * 132 + d4];
            dst[0] = (_Float16)f.x; dst[1] = (_Float16)f.y;
            dst[2] = (_Float16)f.z; dst[3] = (_Float16)f.w;
        }
        __syncthreads();
        #pragma unroll
        for (int p = 0; p < 4; ++p) {
            const int idx = p * 256 + tid;   // g*64 + lane
            const int g = idx >> 6;          // n8*2 + kc
            const int lane2 = idx & 63;
            const int n8 = g >> 1, kc = g & 1;
            const int l15v = lane2 & 15, quadv = lane2 >> 4;
            half8 h;
            #pragma unroll
            for (int j = 0; j < 8; ++j) {
                const int col = kc * 32 + quadv * 8 + j;
                const int w = (col & 3) * 16 + (col >> 2);
                h[j] = vls[w * 132 + n8 * 16 + l15v];
            }
            *(half8*)(vt2 + ((size_t)b * 1024 + idx) * 8) = h;
        }
    } else {
        const int m = (bid - 64) * 2 + (tid >> 7);   // 0..127
        const int d = tid & 127;
        float sk = 0.f, sv = 0.f;
        if (m < kM) {
            const int base = m * kST;
            #pragma unroll
            for (int i = 0; i < kKS; ++i) {
                sk += k[(size_t)(base + i) * kD + d];
                sv += v[(size_t)(base + i) * kD + d];
            }
            sk *= (1.0f / kKS);
            sv *= (1.0f / kKS);
        }
        const short hi = f2bf(sk);
        const short lo = f2bf(sk - b2f(hi));
        const int mt = m >> 4, l15m = m & 15;
        const int c = d >> 5, quadv = (d >> 3) & 3, j = d & 7;
        const int kdst = ((mt * 4 + c) * 64 + quadv * 16 + l15m) * 8 + j;
        ck2h[kdst] = hi;
        ck2l[kdst] = lo;
        const int nt = d >> 4, l15d = d & 15;
        const int pc = (m & 64) + 4 * (m & 15) + ((m & 63) >> 4);
        const int cp = pc >> 5, quadp = (pc >> 3) & 3, jp = pc & 7;
        cv2[((nt * 4 + cp) * 64 + quadp * 16 + l15d) * 8 + jp] = f2bf(sv);
    }
}

// ---------------------------------------------------------------------
// Fused NSA kernel, 2 waves per query (block=128, grid=T, t=2047-bid).
// R10 changes vs R9 (proven baseline):
//  - scores in log2 domain (q scaled by kScale*log2e) -> all exps are
//    bare exp2f (one v_exp_f32, no mul); merge uses exp2f consistently.
//  - Phase B processes the wave's assigned blocks TWO AT A TIME with a
//    joint online-softmax update (max is associative): one alpha, one
//    pair of reduce shuffles, one P-write->read LDS drain, one O-rescale
//    per pair -> ~35% fewer serial-chain cycles/unit + cross-block ILP.
//    Mixed (sel,swa) flags fold into lane masks; per-block PV is
//    branch-skipped.  P slab: block1 cols 0-63, block2 cols 64-127.
// __launch_bounds__(128,1): R5/R6 lesson — tighter caps spill.
// ---------------------------------------------------------------------
__global__ __launch_bounds__(128, 1) void k_nsa(
        const float* __restrict__ q, const float* __restrict__ cw,
        const short* __restrict__ ck2h, const short* __restrict__ ck2l,
        const short* __restrict__ cv2, const short* __restrict__ kb2,
        const _Float16* __restrict__ vt2, float* __restrict__ out) {
    const int tid = threadIdx.x;
    const int wave = tid >> 6;
    const int lane = tid & 63;
    const int l15 = lane & 15;
    const int quad = lane >> 4;
    const int t = kT - 1 - blockIdx.x;   // LPT: heavy first

    __shared__ float sp[kNB];
    __shared__ unsigned selm_s;
    __shared__ short ocst[64 * kOC];                 // ocmp stash (wave0 writes)
    __shared__ __align__(16) char ureg[2 * kUW];     // per-wave overlay regions

    char* const myreg = ureg + wave * kUW;
    _Float16* const PSw = (_Float16*)myreg;                     // 16*144*2 = 4608 B
    _Float16* const PWw = (_Float16*)(myreg + 16 * kPS2 * 2);   // next 4608 B

    // ---- q head=l15, scaled by kScale*log2e, split hi/lo bf16 ----
    short8 qh[4], ql[4];
    {
        const float* qp = q + ((size_t)t * kHQ + l15) * kD + quad * 8;
        #pragma unroll
        for (int c = 0; c < 4; ++c) {
            const float4 f0 = *(const float4*)(qp + c * 32);
            const float4 f1 = *(const float4*)(qp + c * 32 + 4);
            const float xs[8] = {f0.x, f0.y, f0.z, f0.w, f1.x, f1.y, f1.z, f1.w};
            #pragma unroll
            for (int j = 0; j < 8; ++j) {
                const float x = xs[j] * kScaleL2;
                const short h = f2bf(x);
                qh[c][j] = h;
                ql[c][j] = f2bf(x - b2f(h));
            }
        }
    }

    const int nvalid = (t >= kKS - 1) ? min(kM, (t - (kKS - 1)) / kST + 1) : 0;
    const int cur = t >> 6;

    // ================= Phase A (wave0 only), log2-domain =================
    if (wave == 0) {
        short* const p_lds = (short*)ureg;   // wave0 region, dead before Phase B
        constexpr int kPL = 136;
        floatx4 sacc[8];
        #pragma unroll
        for (int mt = 0; mt < 8; ++mt) {
            sacc[mt] = (floatx4){0, 0, 0, 0};
            #pragma unroll
            for (int c = 0; c < 4; ++c) {
                const short8 Ah = *(const short8*)(ck2h + ((mt * 4 + c) * 64 + lane) * 8);
                const short8 Al = *(const short8*)(ck2l + ((mt * 4 + c) * 64 + lane) * 8);
                sacc[mt] = __builtin_amdgcn_mfma_f32_16x16x32_bf16(Ah, qh[c], sacc[mt], 0, 0, 0);
                sacc[mt] = __builtin_amdgcn_mfma_f32_16x16x32_bf16(Ah, ql[c], sacc[mt], 0, 0, 0);
                sacc[mt] = __builtin_amdgcn_mfma_f32_16x16x32_bf16(Al, qh[c], sacc[mt], 0, 0, 0);
            }
        }
        float e[8][4];
        float mx = kNEG;
        #pragma unroll
        for (int mt = 0; mt < 8; ++mt)
            #pragma unroll
            for (int r = 0; r < 4; ++r) {
                const int m = mt * 16 + quad * 4 + r;
                const float s = (m < nvalid) ? sacc[mt][r] : kNEG;
                e[mt][r] = s;
                mx = fmaxf(mx, s);
            }
        mx = fmaxf(mx, __shfl_xor(mx, 16));
        mx = fmaxf(mx, __shfl_xor(mx, 32));
        float sum = 0.f;
        #pragma unroll
        for (int mt = 0; mt < 8; ++mt)
            #pragma unroll
            for (int r = 0; r < 4; ++r) {
                const int m = mt * 16 + quad * 4 + r;
                const float ev = (m < nvalid) ? exp2f(e[mt][r] - mx) : 0.f;
                e[mt][r] = ev;
                sum += ev;
            }
        sum += __shfl_xor(sum, 16);
        sum += __shfl_xor(sum, 32);
        const float inv = (nvalid > 0) ? (1.f / sum) : 0.f;

        float Z[8], Y[8];
        #pragma unroll
        for (int mt = 0; mt < 8; ++mt) {
            const float p0 = e[mt][0] * inv, p1 = e[mt][1] * inv;
            const float p2 = e[mt][2] * inv, p3 = e[mt][3] * inv;
            e[mt][0] = p0; e[mt][1] = p1; e[mt][2] = p2; e[mt][3] = p3;
            Z[mt] = p0 + p1 + p2 + 0.5f * p3;
            Y[mt] = p3;
        }
        #pragma unroll
        for (int g = 0; g < 2; ++g)
            #pragma unroll
            for (int r = 0; r < 4; ++r) {
                short4v s4;
                s4[0] = f2bf(e[4 * g + 0][r]); s4[1] = f2bf(e[4 * g + 1][r]);
                s4[2] = f2bf(e[4 * g + 2][r]); s4[3] = f2bf(e[4 * g + 3][r]);
                *(short4v*)&p_lds[l15 * kPL + g * 64 + 16 * quad + 4 * r] = s4;
            }
        #pragma unroll
        for (int mt = 0; mt < 8; ++mt) {
            #pragma unroll
            for (int o = 1; o <= 8; o <<= 1) {
                Z[mt] += __shfl_xor(Z[mt], o, 16);
                Y[mt] += __shfl_xor(Y[mt], o, 16);
            }
        }
        const int srcl = ((quad + 3) & 3) * 16 + l15;
        #pragma unroll
        for (int mt = 0; mt < 8; ++mt) {
            const float up  = __shfl(Y[mt], srcl);
            const float upm = __shfl(Y[(mt + 7) & 7], srcl);
            const float pv = quad ? up : (mt ? upm : 0.f);
            const int b = 4 * mt + quad;
            float x = Z[mt] + 0.5f * pv;
            if (b > cur) x = kNEG;
            if (b < kNInit || b == cur) x = 1e30f;
            if (l15 == 0) sp[b] = x;
        }
        bool selp = false;
        if (lane < kNB) {
            const float xv = sp[lane];
            int rank = 0;
            #pragma unroll
            for (int b2 = 0; b2 < kNB; ++b2) {
                const float y = sp[b2];
                rank += (y > xv || (y == xv && b2 < lane)) ? 1 : 0;
            }
            selp = rank < kTopN;
        }
        const unsigned sm = (unsigned)__ballot(selp);
        if (lane == 0) selm_s = sm;

        // cmp PV -> ocst (bf16, same-lane)
        short8 ap[4];
        #pragma unroll
        for (int c = 0; c < 4; ++c)
            ap[c] = *(const short8*)&p_lds[l15 * kPL + c * 32 + quad * 8];
        #pragma unroll
        for (int nt = 0; nt < 8; ++nt) {
            floatx4 oc = (floatx4){0, 0, 0, 0};
            #pragma unroll
            for (int c = 0; c < 4; ++c) {
                const short8 bv = *(const short8*)(cv2 + ((nt * 4 + c) * 64 + lane) * 8);
                oc = __builtin_amdgcn_mfma_f32_16x16x32_bf16(ap[c], bv, oc, 0, 0, 0);
            }
            short4v s4;
            s4[0] = f2bf(oc[0]); s4[1] = f2bf(oc[1]);
            s4[2] = f2bf(oc[2]); s4[3] = f2bf(oc[3]);
            *(short4v*)&ocst[lane * kOC + nt * 4] = s4;
        }
    }
    __syncthreads();

    // ========== Phase B: both waves, alternate blocks, PAIRED ==========
    const unsigned selm = selm_s;
    const int lob = max(0, (t - (kWIN - 1)) >> 6);
    const unsigned lm = 0xFFFFFFFFu >> (31 - cur);
    const unsigned act = (selm & lm) | (lm & ~((1u << lob) - 1u));

    float mS = kNEG, lS = 0.f, mW = kNEG, lW = 0.f;
    floatx4 osel[8], oswa[8];
    #pragma unroll
    for (int n8 = 0; n8 < 8; ++n8) {
        osel[n8] = (floatx4){0, 0, 0, 0};
        oswa[n8] = (floatx4){0, 0, 0, 0};
    }

    unsigned a = act;
    int bi = 0;
    while (true) {
        // pull up to 2 of this wave's assigned blocks (alternating by index)
        int b1 = -1, b2 = -1;
        while (a) {
            const int b = __builtin_ctz(a);
            a &= a - 1u;
            const bool mine = ((bi & 1) != wave);   // wave0: odd, wave1: even
            ++bi;
            if (mine) {
                if (b1 < 0) b1 = b;
                else { b2 = b; break; }
            }
        }
        if (b1 < 0) break;
        const bool has2 = b2 >= 0;
        const int b2c = has2 ? b2 : b1;
        const bool sel1 = (selm >> b1) & 1u, swa1 = b1 >= lob;
        const bool sel2 = has2 && ((selm >> b2) & 1u), swa2 = has2 && (b2 >= lob);
        const bool anyS = sel1 | sel2, anyW = swa1 | swa2;

        // ---- coalesced fragment loads (base + lane*16B + imm) ----
        const short* kbb1 = kb2 + ((size_t)b1 * 1024 + lane) * 8;
        const short* kbb2 = kb2 + ((size_t)b2c * 1024 + lane) * 8;
        short8 kreg1[4][4], kreg2[4][4];
        #pragma unroll
        for (int kt = 0; kt < 4; ++kt)
            #pragma unroll
            for (int c = 0; c < 4; ++c)
                kreg1[kt][c] = *(const short8*)(kbb1 + (kt * 4 + c) * 512);
        if (has2) {
            #pragma unroll
            for (int kt = 0; kt < 4; ++kt)
                #pragma unroll
                for (int c = 0; c < 4; ++c)
                    kreg2[kt][c] = *(const short8*)(kbb2 + (kt * 4 + c) * 512);
        }
        const _Float16* vtb1 = vt2 + ((size_t)b1 * 1024 + lane) * 8;
        const _Float16* vtb2 = vt2 + ((size_t)b2c * 1024 + lane) * 8;
        half8 vreg1[8][2], vreg2[8][2];
        #pragma unroll
        for (int n8 = 0; n8 < 8; ++n8) {
            vreg1[n8][0] = *(const half8*)(vtb1 + (n8 * 2 + 0) * 512);
            vreg1[n8][1] = *(const half8*)(vtb1 + (n8 * 2 + 1) * 512);
        }
        if (has2) {
            #pragma unroll
            for (int n8 = 0; n8 < 8; ++n8) {
                vreg2[n8][0] = *(const half8*)(vtb2 + (n8 * 2 + 0) * 512);
                vreg2[n8][1] = *(const half8*)(vtb2 + (n8 * 2 + 1) * 512);
            }
        }

        // ---- QK for both blocks (independent ILP) ----
        floatx4 acc1[4], acc2[4];
        #pragma unroll
        for (int kt = 0; kt < 4; ++kt) {
            acc1[kt] = (floatx4){0, 0, 0, 0};
            acc2[kt] = (floatx4){0, 0, 0, 0};
            #pragma unroll
            for (int c = 0; c < 4; ++c)
                acc1[kt] = __builtin_amdgcn_mfma_f32_16x16x32_bf16(kreg1[kt][c], qh[c], acc1[kt], 0, 0, 0);
        }
        if (has2) {
            #pragma unroll
            for (int kt = 0; kt < 4; ++kt)
                #pragma unroll
                for (int c = 0; c < 4; ++c)
                    acc2[kt] = __builtin_amdgcn_mfma_f32_16x16x32_bf16(kreg2[kt][c], qh[c], acc2[kt], 0, 0, 0);
        }

        const int kb1o = b1 * kBS + quad * 4;
        const int kb2o = b2c * kBS + quad * 4;

        // ---- joint block max (pair shares the reduce shuffles) ----
        float bmS = kNEG, bmW = kNEG;
        #pragma unroll
        for (int kt = 0; kt < 4; ++kt)
            #pragma unroll
            for (int r = 0; r < 4; ++r) {
                const int key1 = kb1o + kt * 16 + r;
                const float s1 = acc1[kt][r];
                const bool ca1 = key1 <= t;
                const bool wi1 = ca1 && (t - key1) < kWIN;
                if (sel1 && ca1) bmS = fmaxf(bmS, s1);
                if (swa1 && wi1) bmW = fmaxf(bmW, s1);
                const int key2 = kb2o + kt * 16 + r;
                const float s2 = acc2[kt][r];
                const bool ca2 = key2 <= t;
                const bool wi2 = ca2 && (t - key2) < kWIN;
                if (sel2 && ca2) bmS = fmaxf(bmS, s2);
                if (swa2 && wi2) bmW = fmaxf(bmW, s2);
            }
        bmS = fmaxf(bmS, __shfl_xor(bmS, 16));
        bmS = fmaxf(bmS, __shfl_xor(bmS, 32));
        bmW = fmaxf(bmW, __shfl_xor(bmW, 16));
        bmW = fmaxf(bmW, __shfl_xor(bmW, 32));

        const float mSn = anyS ? fmaxf(mS, bmS) : mS;
        const float mWn = anyW ? fmaxf(mW, bmW) : mW;
        const float aS = anyS ? exp2f(mS - mSn) : 1.f;
        const float aW = anyW ? exp2f(mW - mWn) : 1.f;

        // ---- exps + P writes (joint; per-block flags fold into masks) ----
        float sumS = 0.f, sumW = 0.f;
        if (anyS && anyW) {
            const float crv = exp2f(mSn - mWn);
            #pragma unroll
            for (int r = 0; r < 4; ++r) {
                half4v hs1, hw1, hs2, hw2;
                #pragma unroll
                for (int kt = 0; kt < 4; ++kt) {
                    const int key1 = kb1o + kt * 16 + r;
                    const bool ca1 = key1 <= t;
                    const bool wi1 = ca1 && (t - key1) < kWIN;
                    const float e01 = ca1 ? exp2f(acc1[kt][r] - mSn) : 0.f;
                    const float es1 = sel1 ? e01 : 0.f;
                    const float ew1 = (swa1 && wi1) ? e01 * crv : 0.f;
                    sumS += es1; sumW += ew1;
                    hs1[kt] = (_Float16)es1; hw1[kt] = (_Float16)ew1;
                    const int key2 = kb2o + kt * 16 + r;
                    const bool ca2 = key2 <= t;
                    const bool wi2 = ca2 && (t - key2) < kWIN;
                    const float e02 = ca2 ? exp2f(acc2[kt][r] - mSn) : 0.f;
                    const float es2 = sel2 ? e02 : 0.f;
                    const float ew2 = (swa2 && wi2) ? e02 * crv : 0.f;
                    sumS += es2; sumW += ew2;
                    hs2[kt] = (_Float16)es2; hw2[kt] = (_Float16)ew2;
                }
                const int prow = l15 * kPS2 + 16 * quad + 4 * r;
                *(half4v*)&PSw[prow] = hs1;
                *(half4v*)&PSw[prow + 64] = hs2;
                *(half4v*)&PWw[prow] = hw1;
                *(half4v*)&PWw[prow + 64] = hw2;
            }
        } else if (anyS) {
            #pragma unroll
            for (int r = 0; r < 4; ++r) {
                half4v hs1, hs2;
                #pragma unroll
                for (int kt = 0; kt < 4; ++kt) {
                    const int key1 = kb1o + kt * 16 + r;
                    const float es1 = (sel1 && key1 <= t) ? exp2f(acc1[kt][r] - mSn) : 0.f;
                    const int key2 = kb2o + kt * 16 + r;
                    const float es2 = (sel2 && key2 <= t) ? exp2f(acc2[kt][r] - mSn) : 0.f;
                    sumS += es1 + es2;
                    hs1[kt] = (_Float16)es1; hs2[kt] = (_Float16)es2;
                }
                const int prow = l15 * kPS2 + 16 * quad + 4 * r;
                *(half4v*)&PSw[prow] = hs1;
                *(half4v*)&PSw[prow + 64] = hs2;
            }
        } else {
            #pragma unroll
            for (int r = 0; r < 4; ++r) {
                half4v hw1, hw2;
                #pragma unroll
                for (int kt = 0; kt < 4; ++kt) {
                    const int key1 = kb1o + kt * 16 + r;
                    const bool wi1 = key1 <= t && (t - key1) < kWIN;
                    const float ew1 = (swa1 && wi1) ? exp2f(acc1[kt][r] - mWn) : 0.f;
                    const int key2 = kb2o + kt * 16 + r;
                    const bool wi2 = key2 <= t && (t - key2) < kWIN;
                    const float ew2 = (swa2 && wi2) ? exp2f(acc2[kt][r] - mWn) : 0.f;
                    sumW += ew1 + ew2;
                    hw1[kt] = (_Float16)ew1; hw2[kt] = (_Float16)ew2;
                }
                const int prow = l15 * kPS2 + 16 * quad + 4 * r;
                *(half4v*)&PWw[prow] = hw1;
                *(half4v*)&PWw[prow + 64] = hw2;
            }
        }
        sumS += __shfl_xor(sumS, 16);
        sumS += __shfl_xor(sumS, 32);
        sumW += __shfl_xor(sumW, 16);
        sumW += __shfl_xor(sumW, 32);
        lS = lS * aS + sumS; mS = mSn;   // safe when inactive: aS=1, sum=0
        lW = lW * aW + sumW; mW = mWn;

        // ---- PV for the pair: one rescale, per-block MFMAs ----
        if (anyS) {
            float aSh[4];
            #pragma unroll
            for (int r = 0; r < 4; ++r) aSh[r] = __shfl(aS, quad * 4 + r);
            half8 ap1[2], ap2[2];
            #pragma unroll
            for (int kc = 0; kc < 2; ++kc) {
                ap1[kc] = *(const half8*)&PSw[l15 * kPS2 + kc * 32 + quad * 8];
                ap2[kc] = *(const half8*)&PSw[l15 * kPS2 + 64 + kc * 32 + quad * 8];
            }
            #pragma unroll
            for (int n8 = 0; n8 < 8; ++n8) {
                #pragma unroll
                for (int r = 0; r < 4; ++r) osel[n8][r] *= aSh[r];
                if (sel1) {
                    osel[n8] = __builtin_amdgcn_mfma_f32_16x16x32_f16(ap1[0], vreg1[n8][0], osel[n8], 0, 0, 0);
                    osel[n8] = __builtin_amdgcn_mfma_f32_16x16x32_f16(ap1[1], vreg1[n8][1], osel[n8], 0, 0, 0);
                }
                if (sel2) {
                    osel[n8] = __builtin_amdgcn_mfma_f32_16x16x32_f16(ap2[0], vreg2[n8][0], osel[n8], 0, 0, 0);
                    osel[n8] = __builtin_amdgcn_mfma_f32_16x16x32_f16(ap2[1], vreg2[n8][1], osel[n8], 0, 0, 0);
                }
            }
        }
        if (anyW) {
            float aWh[4];
            #pragma unroll
            for (int r = 0; r < 4; ++r) aWh[r] = __shfl(aW, quad * 4 + r);
            half8 ap1[2], ap2[2];
            #pragma unroll
            for (int kc = 0; kc < 2; ++kc) {
                ap1[kc] = *(const half8*)&PWw[l15 * kPS2 + kc * 32 + quad * 8];
                ap2[kc] = *(const half8*)&PWw[l15 * kPS2 + 64 + kc * 32 + quad * 8];
            }
            #pragma unroll
            for (int n8 = 0; n8 < 8; ++n8) {
                #pragma unroll
                for (int r = 0; r < 4; ++r) oswa[n8][r] *= aWh[r];
                if (swa1) {
                    oswa[n8] = __builtin_amdgcn_mfma_f32_16x16x32_f16(ap1[0], vreg1[n8][0], oswa[n8], 0, 0, 0);
                    oswa[n8] = __builtin_amdgcn_mfma_f32_16x16x32_f16(ap1[1], vreg1[n8][1], oswa[n8], 0, 0, 0);
                }
                if (swa2) {
                    oswa[n8] = __builtin_amdgcn_mfma_f32_16x16x32_f16(ap2[0], vreg2[n8][0], oswa[n8], 0, 0, 0);
                    oswa[n8] = __builtin_amdgcn_mfma_f32_16x16x32_f16(ap2[1], vreg2[n8][1], oswa[n8], 0, 0, 0);
                }
            }
        }
    }

    // ---- dump partial state to this wave's region (overlays dead PS/PW) ----
    {
        short* const oxSw = (short*)myreg;
        short* const oxWw = (short*)(myreg + 64 * kOC * 2);
        float* const mlw  = (float*)(myreg + 2 * 64 * kOC * 2);
        #pragma unroll
        for (int n8 = 0; n8 < 8; ++n8) {
            short4v s4, w4;
            #pragma unroll
            for (int r = 0; r < 4; ++r) {
                s4[r] = f2bf(osel[n8][r]);
                w4[r] = f2bf(oswa[n8][r]);
            }
            *(short4v*)&oxSw[lane * kOC + n8 * 4] = s4;
            *(short4v*)&oxWw[lane * kOC + n8 * 4] = w4;
        }
        if (quad == 0) *(float4*)&mlw[l15 * 4] = make_float4(mS, lS, mW, lW);
    }
    __syncthreads();

    // ---- merged epilogue: log-sum-exp combine (log2 domain) ----
    const short* const oxS0 = (const short*)ureg;
    const short* const oxW0 = (const short*)(ureg + 64 * kOC * 2);
    const float* const ml0  = (const float*)(ureg + 2 * 64 * kOC * 2);
    const short* const oxS1 = (const short*)(ureg + kUW);
    const short* const oxW1 = (const short*)(ureg + kUW + 64 * kOC * 2);
    const float* const ml1  = (const float*)(ureg + kUW + 2 * 64 * kOC * 2);
    const int n8lo = wave * 4;

    #pragma unroll
    for (int r = 0; r < 4; ++r) {
        const int h = quad * 4 + r;
        const float4 a0 = *(const float4*)&ml0[h * 4];   // mS0,lS0,mW0,lW0
        const float4 a1 = *(const float4*)&ml1[h * 4];
        const float mMS = fmaxf(a0.x, a1.x);
        const float c0S = exp2f(a0.x - mMS);
        const float c1S = exp2f(a1.x - mMS);
        const float liS = 1.f / (a0.y * c0S + a1.y * c1S);
        const float mMW = fmaxf(a0.z, a1.z);
        const float c0W = exp2f(a0.z - mMW);
        const float c1W = exp2f(a1.z - mMW);
        const float liW = 1.f / (a0.w * c0W + a1.w * c1W);
        const float cwa = cw[((size_t)t * kHQ + h) * 3 + 0];
        const float cwb = cw[((size_t)t * kHQ + h) * 3 + 1];
        const float cwc = cw[((size_t)t * kHQ + h) * 3 + 2];
        const float w0 = 1.f / (1.f + __expf(-cwa));
        const float w1 = 1.f / (1.f + __expf(-cwb));
        const float w2 = 1.f / (1.f + __expf(-cwc));
        float* op = out + ((size_t)t * kHQ + h) * kD + l15;
        #pragma unroll
        for (int i = 0; i < 4; ++i) {
            const int n8 = n8lo + i;
            const int j = n8 * 4 + r;
            const float sM = (b2f(oxS0[lane * kOC + j]) * c0S + b2f(oxS1[lane * kOC + j]) * c1S) * liS;
            const float wM = (b2f(oxW0[lane * kOC + j]) * c0W + b2f(oxW1[lane * kOC + j]) * c1W) * liW;
            const float oc = b2f(ocst[lane * kOC + j]);
            op[n8 * 16] = w0 * oc + w1 * sM + w2 * wM;
        }
    }
}

// ---------------------------------------------------------------------
extern "C" void kernel_launch(void* const* d_in, const int* in_sizes, int n_in,
                              void* d_out, int out_size, void* d_ws, size_t ws_size,
                              hipStream_t stream) {
    const float* q  = (const float*)d_in[0];
    const float* k  = (const float*)d_in[1];
    const float* v  = (const float*)d_in[2];
    const float* cw = (const float*)d_in[3];
    float* out = (float*)d_out;

    short* kb2    = (short*)d_ws;                         // 32*1024*8 shorts (512 KB)
    _Float16* vt2 = (_Float16*)(kb2 + 32 * 1024 * 8);     // 512 KB
    short* ck2h   = (short*)(vt2 + 32 * 1024 * 8);        // 32 KB
    short* ck2l   = ck2h + 32 * 64 * 8;                   // 32 KB
    short* cv2    = ck2l + 32 * 64 * 8;                   // 32 KB

    k_stage<<<dim3(128), dim3(256), 0, stream>>>(k, v, kb2, vt2, ck2h, ck2l, cv2);
    k_nsa<<<dim3(kT), dim3(128), 0, stream>>>(q, cw, ck2h, ck2l, cv2, kb2, vt2, out);
}

// Round 11
// 152.764 us; speedup vs baseline: 1.4166x; 1.4166x over previous
//
#include <hip/hip_runtime.h>
#include <math.h>

// ---- NSA hyperparameters (compile-time, matches reference config) ----
constexpr int kT    = 2048;
constexpr int kHQ   = 16;
constexpr int kD    = 128;
constexpr int kKS   = 32;
constexpr int kST   = 16;
constexpr int kBS   = 64;
constexpr int kM    = (kT - kKS) / kST + 1;   // 127 compressed tokens
constexpr int kNB   = (kT + kBS - 1) / kBS;   // 32 selection blocks
constexpr int kTopN = 16;
constexpr int kNInit = 2;
constexpr int kWIN  = 512;
constexpr float kNEG = -1e30f;
constexpr float kScale = 0.08838834764831845f;      // 128^-0.5
// log2-domain scores: fold log2(e) into q scaling -> bare exp2 everywhere
constexpr float kScaleL2 = kScale * 1.4426950408889634f;

constexpr int kPSt = 72;    // P slab row stride (fp16)
constexpr int kPL  = 136;   // Phase-A p_lds row stride (bf16 shorts)

// ---- ureg layout (bytes).  Per-wave regions; overlays are time-disjoint.
// wave0: [oxS0 4096][PS0 slab 2304]          (Phase-A p_lds 4352 overlays front)
// wave1: [oxS1 4096][PS1 slab 2304 == oxW1 4096][ml1 256]
constexpr int kOxS0 = 0;
constexpr int kPS0  = 4096;
constexpr int kOxS1 = 6400;
constexpr int kPS1  = 10496;
constexpr int kOxW1 = 10496;   // overlays PS1 (written after last P read)
constexpr int kMl1  = 14592;
constexpr int kUreg = 15104;

typedef __attribute__((ext_vector_type(8))) short short8;
typedef __attribute__((ext_vector_type(4))) short short4v;
typedef __attribute__((ext_vector_type(8))) _Float16 half8;
typedef __attribute__((ext_vector_type(4))) _Float16 half4v;
typedef __attribute__((ext_vector_type(4))) float floatx4;

// RNE float -> bf16 bits
__device__ inline short f2bf(float x) {
    unsigned u = __float_as_uint(x);
    unsigned r = (u + 0x7fffu + ((u >> 16) & 1u)) >> 16;
    return (short)r;
}
__device__ inline float b2f(short h) {
    return __uint_as_float(((unsigned)(unsigned short)h) << 16);
}

// ---------------------------------------------------------------------
// K1: FRAGMENT-ORDERED staging (R9-proven, unchanged).
// ---------------------------------------------------------------------
__global__ __launch_bounds__(256) void k_stage(
        const float* __restrict__ k, const float* __restrict__ v,
        short* __restrict__ kb2, _Float16* __restrict__ vt2,
        short* __restrict__ ck2h, short* __restrict__ ck2l,
        short* __restrict__ cv2) {
    const int bid = blockIdx.x;
    const int tid = threadIdx.x;
    __shared__ _Float16 vls[64 * 132];

    if (bid < 32) {
        const int b = bid;
        #pragma unroll
        for (int p = 0; p < 4; ++p) {
            const int idx = p * 256 + tid;          // 0..1023 = g*64 + lane
            const int g = idx >> 6;                  // kt*4 + c
            const int lane2 = idx & 63;
            const int kt = g >> 2, c = g & 3;
            const int l15v = lane2 & 15, quadv = lane2 >> 4;
            const float* src = k + (size_t)(b * 64 + kt * 16 + l15v) * kD + c * 32 + quadv * 8;
            const float4 f0 = *(const float4*)(src);
            const float4 f1 = *(const float4*)(src + 4);
            short8 s;
            s[0] = f2bf(f0.x); s[1] = f2bf(f0.y); s[2] = f2bf(f0.z); s[3] = f2bf(f0.w);
            s[4] = f2bf(f1.x); s[5] = f2bf(f1.y); s[6] = f2bf(f1.z); s[7] = f2bf(f1.w);
            *(short8*)(kb2 + ((size_t)b * 1024 + idx) * 8) = s;
        }
    } else if (bid < 64) {
        const int b = bid - 32;
        #pragma unroll
        for (int p = 0; p < 8; ++p) {
            const int idx = p * 256 + tid;   // 2048 float4-slots
            const int r = idx >> 5;
            const int d4 = (idx & 31) * 4;
            const float4 f = *(const float4*)(v + (size_t)(b * 64 + r) * kD + d4);
            _Float16* dst = &vls[r * 132 + d4];
            dst[0] = (_Float16)f.x; dst[1] = (_Float16)f.y;
            dst[2] = (_Float16)f.z; dst[3] = (_Float16)f.w;
        }
        __syncthreads();
        #pragma unroll
        for (int p = 0; p < 4; ++p) {
            const int idx = p * 256 + tid;   // g*64 + lane
            const int g = idx >> 6;          // n8*2 + kc
            const int lane2 = idx & 63;
            const int n8 = g >> 1, kc = g & 1;
            const int l15v = lane2 & 15, quadv = lane2 >> 4;
            half8 h;
            #pragma unroll
            for (int j = 0; j < 8; ++j) {
                const int col = kc * 32 + quadv * 8 + j;
                const int w = (col & 3) * 16 + (col >> 2);
                h[j] = vls[w * 132 + n8 * 16 + l15v];
            }
            *(half8*)(vt2 + ((size_t)b * 1024 + idx) * 8) = h;
        }
    } else {
        const int m = (bid - 64) * 2 + (tid >> 7);   // 0..127
        const int d = tid & 127;
        float sk = 0.f, sv = 0.f;
        if (m < kM) {
            const int base = m * kST;
            #pragma unroll
            for (int i = 0; i < kKS; ++i) {
                sk += k[(size_t)(base + i) * kD + d];
                sv += v[(size_t)(base + i) * kD + d];
            }
            sk *= (1.0f / kKS);
            sv *= (1.0f / kKS);
        }
        const short hi = f2bf(sk);
        const short lo = f2bf(sk - b2f(hi));
        const int mt = m >> 4, l15m = m & 15;
        const int c = d >> 5, quadv = (d >> 3) & 3, j = d & 7;
        const int kdst = ((mt * 4 + c) * 64 + quadv * 16 + l15m) * 8 + j;
        ck2h[kdst] = hi;
        ck2l[kdst] = lo;
        const int nt = d >> 4, l15d = d & 15;
        const int pc = (m & 64) + 4 * (m & 15) + ((m & 63) >> 4);
        const int cp = pc >> 5, quadp = (pc >> 3) & 3, jp = pc & 7;
        cv2[((nt * 4 + cp) * 64 + quadp * 16 + l15d) * 8 + jp] = f2bf(sv);
    }
}

// ---------------------------------------------------------------------
// Fused NSA, 2 waves/query (block=128, grid=T, t=2047-bid).
// R11: occupancy attack.  VGPR quantization steps at 64/128/256 (m69);
// every prior round sat at (128,256] -> 8 waves/CU.  Force <=128 via
// __launch_bounds__(128,4) + register diet:
//  - Phase B split into SEL pass then SWA pass: only ONE 32-reg
//    accumulator live at a time (osel dumped to LDS at pass-1 end;
//    oswa reuses its registers).
//  - K loaded in 2x16-reg halves; V in 2x16-reg halves around PV halves.
// Merge: wave1 dumps oswa+stats; one barrier; wave0 (oswa in regs,
// osel from LDS) LSE-merges and does all stores.
// ---------------------------------------------------------------------
__global__ __launch_bounds__(128, 4) void k_nsa(
        const float* __restrict__ q, const float* __restrict__ cw,
        const short* __restrict__ ck2h, const short* __restrict__ ck2l,
        const short* __restrict__ cv2, const short* __restrict__ kb2,
        const _Float16* __restrict__ vt2, float* __restrict__ out) {
    const int tid = threadIdx.x;
    const int wave = tid >> 6;
    const int lane = tid & 63;
    const int l15 = lane & 15;
    const int quad = lane >> 4;
    const int t = kT - 1 - blockIdx.x;   // LPT: heavy first

    __shared__ float sp[kNB];
    __shared__ unsigned selm_s;
    __shared__ short ocst[64 * 32];                  // 4096 B (wave0 writes/reads)
    __shared__ __align__(16) char ureg[kUreg];

    _Float16* const PSme = (_Float16*)(ureg + (wave ? kPS1 : kPS0));
    short* const oxMine  = (short*)(ureg + (wave ? kOxS1 : kOxS0));

    // ---- q head=l15, scaled by kScale*log2e -> bf16 hi (both waves) ----
    short8 qh[4];
    {
        const float* qp = q + ((size_t)t * kHQ + l15) * kD + quad * 8;
        #pragma unroll
        for (int c = 0; c < 4; ++c) {
            const float4 f0 = *(const float4*)(qp + c * 32);
            const float4 f1 = *(const float4*)(qp + c * 32 + 4);
            const float xs[8] = {f0.x, f0.y, f0.z, f0.w, f1.x, f1.y, f1.z, f1.w};
            #pragma unroll
            for (int j = 0; j < 8; ++j) qh[c][j] = f2bf(xs[j] * kScaleL2);
        }
    }

    const int nvalid = (t >= kKS - 1) ? min(kM, (t - (kKS - 1)) / kST + 1) : 0;
    const int cur = t >> 6;

    // ================= Phase A (wave0 only), log2-domain =================
    if (wave == 0) {
        // lo-half of q built locally (dies with Phase A)
        short8 ql[4];
        {
            const float* qp = q + ((size_t)t * kHQ + l15) * kD + quad * 8;
            #pragma unroll
            for (int c = 0; c < 4; ++c) {
                const float4 f0 = *(const float4*)(qp + c * 32);
                const float4 f1 = *(const float4*)(qp + c * 32 + 4);
                const float xs[8] = {f0.x, f0.y, f0.z, f0.w, f1.x, f1.y, f1.z, f1.w};
                #pragma unroll
                for (int j = 0; j < 8; ++j)
                    ql[c][j] = f2bf(xs[j] * kScaleL2 - b2f(qh[c][j]));
            }
        }
        short* const p_lds = (short*)ureg;   // 4352 B, dead before pass 1
        floatx4 sacc[8];
        #pragma unroll
        for (int mt = 0; mt < 8; ++mt) {
            sacc[mt] = (floatx4){0, 0, 0, 0};
            #pragma unroll
            for (int c = 0; c < 4; ++c) {
                const short8 Ah = *(const short8*)(ck2h + ((mt * 4 + c) * 64 + lane) * 8);
                const short8 Al = *(const short8*)(ck2l + ((mt * 4 + c) * 64 + lane) * 8);
                sacc[mt] = __builtin_amdgcn_mfma_f32_16x16x32_bf16(Ah, qh[c], sacc[mt], 0, 0, 0);
                sacc[mt] = __builtin_amdgcn_mfma_f32_16x16x32_bf16(Ah, ql[c], sacc[mt], 0, 0, 0);
                sacc[mt] = __builtin_amdgcn_mfma_f32_16x16x32_bf16(Al, qh[c], sacc[mt], 0, 0, 0);
            }
        }
        // mask + max (sacc reused in place: scores -> exps -> probs)
        float mx = kNEG;
        #pragma unroll
        for (int mt = 0; mt < 8; ++mt)
            #pragma unroll
            for (int r = 0; r < 4; ++r) {
                const int m = mt * 16 + quad * 4 + r;
                const float s = (m < nvalid) ? sacc[mt][r] : kNEG;
                sacc[mt][r] = s;
                mx = fmaxf(mx, s);
            }
        mx = fmaxf(mx, __shfl_xor(mx, 16));
        mx = fmaxf(mx, __shfl_xor(mx, 32));
        float sum = 0.f;
        #pragma unroll
        for (int mt = 0; mt < 8; ++mt)
            #pragma unroll
            for (int r = 0; r < 4; ++r) {
                const int m = mt * 16 + quad * 4 + r;
                const float ev = (m < nvalid) ? exp2f(sacc[mt][r] - mx) : 0.f;
                sacc[mt][r] = ev;
                sum += ev;
            }
        sum += __shfl_xor(sum, 16);
        sum += __shfl_xor(sum, 32);
        const float inv = (nvalid > 0) ? (1.f / sum) : 0.f;

        float Z[8], Y[8];
        #pragma unroll
        for (int mt = 0; mt < 8; ++mt) {
            const float p0 = sacc[mt][0] * inv, p1 = sacc[mt][1] * inv;
            const float p2 = sacc[mt][2] * inv, p3 = sacc[mt][3] * inv;
            sacc[mt][0] = p0; sacc[mt][1] = p1; sacc[mt][2] = p2; sacc[mt][3] = p3;
            Z[mt] = p0 + p1 + p2 + 0.5f * p3;
            Y[mt] = p3;
        }
        #pragma unroll
        for (int g = 0; g < 2; ++g)
            #pragma unroll
            for (int r = 0; r < 4; ++r) {
                short4v s4;
                s4[0] = f2bf(sacc[4 * g + 0][r]); s4[1] = f2bf(sacc[4 * g + 1][r]);
                s4[2] = f2bf(sacc[4 * g + 2][r]); s4[3] = f2bf(sacc[4 * g + 3][r]);
                *(short4v*)&p_lds[l15 * kPL + g * 64 + 16 * quad + 4 * r] = s4;
            }
        #pragma unroll
        for (int mt = 0; mt < 8; ++mt) {
            #pragma unroll
            for (int o = 1; o <= 8; o <<= 1) {
                Z[mt] += __shfl_xor(Z[mt], o, 16);
                Y[mt] += __shfl_xor(Y[mt], o, 16);
            }
        }
        const int srcl = ((quad + 3) & 3) * 16 + l15;
        #pragma unroll
        for (int mt = 0; mt < 8; ++mt) {
            const float up  = __shfl(Y[mt], srcl);
            const float upm = __shfl(Y[(mt + 7) & 7], srcl);
            const float pv = quad ? up : (mt ? upm : 0.f);
            const int b = 4 * mt + quad;
            float x = Z[mt] + 0.5f * pv;
            if (b > cur) x = kNEG;
            if (b < kNInit || b == cur) x = 1e30f;
            if (l15 == 0) sp[b] = x;
        }
        bool selp = false;
        if (lane < kNB) {
            const float xv = sp[lane];
            int rank = 0;
            #pragma unroll
            for (int b2 = 0; b2 < kNB; ++b2) {
                const float y = sp[b2];
                rank += (y > xv || (y == xv && b2 < lane)) ? 1 : 0;
            }
            selp = rank < kTopN;
        }
        const unsigned sm = (unsigned)__ballot(selp);
        if (lane == 0) selm_s = sm;

        // cmp PV -> ocst (bf16, same-lane)
        short8 ap[4];
        #pragma unroll
        for (int c = 0; c < 4; ++c)
            ap[c] = *(const short8*)&p_lds[l15 * kPL + c * 32 + quad * 8];
        #pragma unroll
        for (int nt = 0; nt < 8; ++nt) {
            floatx4 oc = (floatx4){0, 0, 0, 0};
            #pragma unroll
            for (int c = 0; c < 4; ++c) {
                const short8 bv = *(const short8*)(cv2 + ((nt * 4 + c) * 64 + lane) * 8);
                oc = __builtin_amdgcn_mfma_f32_16x16x32_bf16(ap[c], bv, oc, 0, 0, 0);
            }
            short4v s4;
            s4[0] = f2bf(oc[0]); s4[1] = f2bf(oc[1]);
            s4[2] = f2bf(oc[2]); s4[3] = f2bf(oc[3]);
            *(short4v*)&ocst[lane * 32 + nt * 4] = s4;
        }
    }
    __syncthreads();

    const unsigned selm = selm_s;
    const int lob = max(0, (t - (kWIN - 1)) >> 6);
    const unsigned lm = 0xFFFFFFFFu >> (31 - cur);

    float mS = kNEG, lS = 0.f;
    float mW = kNEG, lW = 0.f;

    // ================== PASS 1: SEL (osel in regs) ==================
    {
        floatx4 osel[8];
        #pragma unroll
        for (int n8 = 0; n8 < 8; ++n8) osel[n8] = (floatx4){0, 0, 0, 0};

        unsigned a = selm & lm;
        int bi = 0;
        while (a) {
            const int b = __builtin_ctz(a);
            a &= a - 1u;
            const bool mine = ((bi & 1) != wave);
            ++bi;
            if (!mine) continue;

            const short* kbb = kb2 + ((size_t)b * 1024 + lane) * 8;
            floatx4 acc[4];
            {
                short8 kreg[2][4];
                #pragma unroll
                for (int kt = 0; kt < 2; ++kt)
                    #pragma unroll
                    for (int c = 0; c < 4; ++c)
                        kreg[kt][c] = *(const short8*)(kbb + (kt * 4 + c) * 512);
                #pragma unroll
                for (int kt = 0; kt < 2; ++kt) {
                    acc[kt] = (floatx4){0, 0, 0, 0};
                    #pragma unroll
                    for (int c = 0; c < 4; ++c)
                        acc[kt] = __builtin_amdgcn_mfma_f32_16x16x32_bf16(kreg[kt][c], qh[c], acc[kt], 0, 0, 0);
                }
                #pragma unroll
                for (int kt = 0; kt < 2; ++kt)
                    #pragma unroll
                    for (int c = 0; c < 4; ++c)
                        kreg[kt][c] = *(const short8*)(kbb + ((kt + 2) * 4 + c) * 512);
                #pragma unroll
                for (int kt = 0; kt < 2; ++kt) {
                    acc[kt + 2] = (floatx4){0, 0, 0, 0};
                    #pragma unroll
                    for (int c = 0; c < 4; ++c)
                        acc[kt + 2] = __builtin_amdgcn_mfma_f32_16x16x32_bf16(kreg[kt][c], qh[c], acc[kt + 2], 0, 0, 0);
                }
            }

            const int kbo = b * kBS + quad * 4;
            float bm = kNEG;
            #pragma unroll
            for (int kt = 0; kt < 4; ++kt)
                #pragma unroll
                for (int r = 0; r < 4; ++r) {
                    const int key = kbo + kt * 16 + r;
                    if (key <= t) bm = fmaxf(bm, acc[kt][r]);
                }
            bm = fmaxf(bm, __shfl_xor(bm, 16));
            bm = fmaxf(bm, __shfl_xor(bm, 32));
            const float mn = fmaxf(mS, bm);
            const float al = exp2f(mS - mn);

            float sum = 0.f;
            #pragma unroll
            for (int r = 0; r < 4; ++r) {
                half4v hs;
                #pragma unroll
                for (int kt = 0; kt < 4; ++kt) {
                    const int key = kbo + kt * 16 + r;
                    const float e0 = (key <= t) ? exp2f(acc[kt][r] - mn) : 0.f;
                    sum += e0;
                    hs[kt] = (_Float16)e0;
                }
                *(half4v*)&PSme[l15 * kPSt + 16 * quad + 4 * r] = hs;
            }
            sum += __shfl_xor(sum, 16);
            sum += __shfl_xor(sum, 32);
            lS = lS * al + sum; mS = mn;

            float alh[4];
            #pragma unroll
            for (int r = 0; r < 4; ++r) alh[r] = __shfl(al, quad * 4 + r);
            const half8 ap0 = *(const half8*)&PSme[l15 * kPSt + quad * 8];
            const half8 ap1 = *(const half8*)&PSme[l15 * kPSt + 32 + quad * 8];
            const _Float16* vtb = vt2 + ((size_t)b * 1024 + lane) * 8;
            {
                half8 vr[4][2];
                #pragma unroll
                for (int n8 = 0; n8 < 4; ++n8) {
                    vr[n8][0] = *(const half8*)(vtb + (n8 * 2 + 0) * 512);
                    vr[n8][1] = *(const half8*)(vtb + (n8 * 2 + 1) * 512);
                }
                #pragma unroll
                for (int n8 = 0; n8 < 4; ++n8) {
                    #pragma unroll
                    for (int r = 0; r < 4; ++r) osel[n8][r] *= alh[r];
                    osel[n8] = __builtin_amdgcn_mfma_f32_16x16x32_f16(ap0, vr[n8][0], osel[n8], 0, 0, 0);
                    osel[n8] = __builtin_amdgcn_mfma_f32_16x16x32_f16(ap1, vr[n8][1], osel[n8], 0, 0, 0);
                }
                #pragma unroll
                for (int n8 = 0; n8 < 4; ++n8) {
                    vr[n8][0] = *(const half8*)(vtb + ((n8 + 4) * 2 + 0) * 512);
                    vr[n8][1] = *(const half8*)(vtb + ((n8 + 4) * 2 + 1) * 512);
                }
                #pragma unroll
                for (int n8 = 0; n8 < 4; ++n8) {
                    #pragma unroll
                    for (int r = 0; r < 4; ++r) osel[n8 + 4][r] *= alh[r];
                    osel[n8 + 4] = __builtin_amdgcn_mfma_f32_16x16x32_f16(ap0, vr[n8][0], osel[n8 + 4], 0, 0, 0);
                    osel[n8 + 4] = __builtin_amdgcn_mfma_f32_16x16x32_f16(ap1, vr[n8][1], osel[n8 + 4], 0, 0, 0);
                }
            }
        }

        // dump osel to this wave's oxS region (frees 32 regs for pass 2)
        #pragma unroll
        for (int n8 = 0; n8 < 8; ++n8) {
            short4v s4;
            #pragma unroll
            for (int r = 0; r < 4; ++r) s4[r] = f2bf(osel[n8][r]);
            *(short4v*)&oxMine[lane * 32 + n8 * 4] = s4;
        }
    }

    // ================== PASS 2: SWA (oswa in regs) ==================
    floatx4 oswa[8];
    #pragma unroll
    for (int n8 = 0; n8 < 8; ++n8) oswa[n8] = (floatx4){0, 0, 0, 0};
    {
        unsigned a = lm & ~((1u << lob) - 1u);
        int bi = 0;
        while (a) {
            const int b = __builtin_ctz(a);
            a &= a - 1u;
            const bool mine = ((bi & 1) != wave);
            ++bi;
            if (!mine) continue;

            const short* kbb = kb2 + ((size_t)b * 1024 + lane) * 8;
            floatx4 acc[4];
            {
                short8 kreg[2][4];
                #pragma unroll
                for (int kt = 0; kt < 2; ++kt)
                    #pragma unroll
                    for (int c = 0; c < 4; ++c)
                        kreg[kt][c] = *(const short8*)(kbb + (kt * 4 + c) * 512);
                #pragma unroll
                for (int kt = 0; kt < 2; ++kt) {
                    acc[kt] = (floatx4){0, 0, 0, 0};
                    #pragma unroll
                    for (int c = 0; c < 4; ++c)
                        acc[kt] = __builtin_amdgcn_mfma_f32_16x16x32_bf16(kreg[kt][c], qh[c], acc[kt], 0, 0, 0);
                }
                #pragma unroll
                for (int kt = 0; kt < 2; ++kt)
                    #pragma unroll
                    for (int c = 0; c < 4; ++c)
                        kreg[kt][c] = *(const short8*)(kbb + ((kt + 2) * 4 + c) * 512);
                #pragma unroll
                for (int kt = 0; kt < 2; ++kt) {
                    acc[kt + 2] = (floatx4){0, 0, 0, 0};
                    #pragma unroll
                    for (int c = 0; c < 4; ++c)
                        acc[kt + 2] = __builtin_amdgcn_mfma_f32_16x16x32_bf16(kreg[kt][c], qh[c], acc[kt + 2], 0, 0, 0);
                }
            }

            const int kbo = b * kBS + quad * 4;
            float bm = kNEG;
            #pragma unroll
            for (int kt = 0; kt < 4; ++kt)
                #pragma unroll
                for (int r = 0; r < 4; ++r) {
                    const int key = kbo + kt * 16 + r;
                    if (key <= t && (t - key) < kWIN) bm = fmaxf(bm, acc[kt][r]);
                }
            bm = fmaxf(bm, __shfl_xor(bm, 16));
            bm = fmaxf(bm, __shfl_xor(bm, 32));
            const float mn = fmaxf(mW, bm);
            const float al = exp2f(mW - mn);

            float sum = 0.f;
            #pragma unroll
            for (int r = 0; r < 4; ++r) {
                half4v hw;
                #pragma unroll
                for (int kt = 0; kt < 4; ++kt) {
                    const int key = kbo + kt * 16 + r;
                    const float e0 = (key <= t && (t - key) < kWIN) ? exp2f(acc[kt][r] - mn) : 0.f;
                    sum += e0;
                    hw[kt] = (_Float16)e0;
                }
                *(half4v*)&PSme[l15 * kPSt + 16 * quad + 4 * r] = hw;
            }
            sum += __shfl_xor(sum, 16);
            sum += __shfl_xor(sum, 32);
            lW = lW * al + sum; mW = mn;

            float alh[4];
            #pragma unroll
            for (int r = 0; r < 4; ++r) alh[r] = __shfl(al, quad * 4 + r);
            const half8 ap0 = *(const half8*)&PSme[l15 * kPSt + quad * 8];
            const half8 ap1 = *(const half8*)&PSme[l15 * kPSt + 32 + quad * 8];
            const _Float16* vtb = vt2 + ((size_t)b * 1024 + lane) * 8;
            {
                half8 vr[4][2];
                #pragma unroll
                for (int n8 = 0; n8 < 4; ++n8) {
                    vr[n8][0] = *(const half8*)(vtb + (n8 * 2 + 0) * 512);
                    vr[n8][1] = *(const half8*)(vtb + (n8 * 2 + 1) * 512);
                }
                #pragma unroll
                for (int n8 = 0; n8 < 4; ++n8) {
                    #pragma unroll
                    for (int r = 0; r < 4; ++r) oswa[n8][r] *= alh[r];
                    oswa[n8] = __builtin_amdgcn_mfma_f32_16x16x32_f16(ap0, vr[n8][0], oswa[n8], 0, 0, 0);
                    oswa[n8] = __builtin_amdgcn_mfma_f32_16x16x32_f16(ap1, vr[n8][1], oswa[n8], 0, 0, 0);
                }
                #pragma unroll
                for (int n8 = 0; n8 < 4; ++n8) {
                    vr[n8][0] = *(const half8*)(vtb + ((n8 + 4) * 2 + 0) * 512);
                    vr[n8][1] = *(const half8*)(vtb + ((n8 + 4) * 2 + 1) * 512);
                }
                #pragma unroll
                for (int n8 = 0; n8 < 4; ++n8) {
                    #pragma unroll
                    for (int r = 0; r < 4; ++r) oswa[n8 + 4][r] *= alh[r];
                    oswa[n8 + 4] = __builtin_amdgcn_mfma_f32_16x16x32_f16(ap0, vr[n8][0], oswa[n8 + 4], 0, 0, 0);
                    oswa[n8 + 4] = __builtin_amdgcn_mfma_f32_16x16x32_f16(ap1, vr[n8][1], oswa[n8 + 4], 0, 0, 0);
                }
            }
        }
    }

    // ---- wave1: dump oswa + stats; wave0 keeps them in regs ----
    if (wave == 1) {
        short* const oxW = (short*)(ureg + kOxW1);   // overlays dead PS1
        #pragma unroll
        for (int n8 = 0; n8 < 8; ++n8) {
            short4v w4;
            #pragma unroll
            for (int r = 0; r < 4; ++r) w4[r] = f2bf(oswa[n8][r]);
            *(short4v*)&oxW[lane * 32 + n8 * 4] = w4;
        }
        if (quad == 0)
            *(float4*)&((float*)(ureg + kMl1))[l15 * 4] = make_float4(mS, lS, mW, lW);
    }
    __syncthreads();

    // ---- wave0: LSE merge (log2 domain) + sigmoid combine + all stores ----
    if (wave == 0) {
        const short* const oxS0 = (const short*)(ureg + kOxS0);
        const short* const oxS1 = (const short*)(ureg + kOxS1);
        const short* const oxW1 = (const short*)(ureg + kOxW1);
        const float* const ml1  = (const float*)(ureg + kMl1);

        #pragma unroll
        for (int r = 0; r < 4; ++r) {
            const int h = quad * 4 + r;
            const float m0S = __shfl(mS, h), l0S = __shfl(lS, h);
            const float m0W = __shfl(mW, h), l0W = __shfl(lW, h);
            const float4 a1 = *(const float4*)&ml1[h * 4];   // wave1: mS,lS,mW,lW
            const float mMS = fmaxf(m0S, a1.x);
            const float c0S = exp2f(m0S - mMS);
            const float c1S = exp2f(a1.x - mMS);
            const float liS = 1.f / (l0S * c0S + a1.y * c1S);
            const float mMW = fmaxf(m0W, a1.z);
            const float c0W = exp2f(m0W - mMW);
            const float c1W = exp2f(a1.z - mMW);
            const float liW = 1.f / (l0W * c0W + a1.w * c1W);
            const float cwa = cw[((size_t)t * kHQ + h) * 3 + 0];
            const float cwb = cw[((size_t)t * kHQ + h) * 3 + 1];
            const float cwc = cw[((size_t)t * kHQ + h) * 3 + 2];
            const float w0 = 1.f / (1.f + __expf(-cwa));
            const float w1 = 1.f / (1.f + __expf(-cwb));
            const float w2 = 1.f / (1.f + __expf(-cwc));
            float* op = out + ((size_t)t * kHQ + h) * kD + l15;
            #pragma unroll
            for (int n8 = 0; n8 < 8; ++n8) {
                const int j = n8 * 4 + r;
                const float sM = (b2f(oxS0[lane * 32 + j]) * c0S + b2f(oxS1[lane * 32 + j]) * c1S) * liS;
                const float wM = (oswa[n8][r] * c0W + b2f(oxW1[lane * 32 + j]) * c1W) * liW;
                const float oc = b2f(ocst[lane * 32 + j]);
                op[n8 * 16] = w0 * oc + w1 * sM + w2 * wM;
            }
        }
    }
}

// ---------------------------------------------------------------------
extern "C" void kernel_launch(void* const* d_in, const int* in_sizes, int n_in,
                              void* d_out, int out_size, void* d_ws, size_t ws_size,
                              hipStream_t stream) {
    const float* q  = (const float*)d_in[0];
    const float* k  = (const float*)d_in[1];
    const float* v  = (const float*)d_in[2];
    const float* cw = (const float*)d_in[3];
    float* out = (float*)d_out;

    short* kb2    = (short*)d_ws;                         // 32*1024*8 shorts (512 KB)
    _Float16* vt2 = (_Float16*)(kb2 + 32 * 1024 * 8);     // 512 KB
    short* ck2h   = (short*)(vt2 + 32 * 1024 * 8);        // 32 KB
    short* ck2l   = ck2h + 32 * 64 * 8;                   // 32 KB
    short* cv2    = ck2l + 32 * 64 * 8;                   // 32 KB

    k_stage<<<dim3(128), dim3(256), 0, stream>>>(k, v, kb2, vt2, ck2h, ck2l, cv2);
    k_nsa<<<dim3(kT), dim3(128), 0, stream>>>(q, cw, ck2h, ck2l, cv2, kb2, vt2, out);
}